// Round 1
// baseline (138.189 us; speedup 1.0000x reference)
//
#include <hip/hip_runtime.h>
#include <hip/hip_bf16.h>

// DotInteraction: batch [8192, 100, 128] f32 -> lower-triangle of A·A^T -> [8192, 4950] f32
// One block (4 waves) per batch element. f32->bf16 LDS staging (XOR-swizzled),
// mfma_f32_16x16x32_bf16 over 28 lower-triangle 16x16 tile pairs (7 per wave),
// predicated packed-triangle scatter writes.

#define NB   100
#define DD   128
#define NPAIR 4950   // 100*99/2
#define NTILE 7      // 7*16 = 112 >= 100

typedef __attribute__((ext_vector_type(4))) float  f32x4;
typedef __attribute__((ext_vector_type(8))) short  bf16x8;
typedef __attribute__((ext_vector_type(4))) short  bf16x4;

__device__ __forceinline__ short f2bf(float x) {
    __hip_bfloat16 h = __float2bfloat16(x);   // RNE
    union { __hip_bfloat16 h; short s; } u; u.h = h;
    return u.s;
}

__global__ __launch_bounds__(256, 4)
void DotInteraction_82042465288419_kernel(const float* __restrict__ in,
                                          float* __restrict__ out) {
    // 112 rows (16-padded) x 128 bf16, XOR-swizzled: byte ^= (row&7)<<4
    __shared__ __align__(16) short sA[112 * 128];

    const int b = blockIdx.x;
    const float* Ab = in + (size_t)b * (NB * DD);

    // ---- stage: f32 -> bf16 into swizzled LDS (coalesced float4 loads) ----
    for (int idx = threadIdx.x; idx < NB * DD / 4; idx += 256) {
        const int r  = idx >> 5;          // 32 float4 per row
        const int k4 = idx & 31;
        f32x4 v = *reinterpret_cast<const f32x4*>(Ab + ((size_t)idx << 2));
        bf16x4 h;
        h.x = f2bf(v.x); h.y = f2bf(v.y); h.z = f2bf(v.z); h.w = f2bf(v.w);
        const int byt = ((r << 8) + (k4 << 3)) ^ ((r & 7) << 4);
        *reinterpret_cast<bf16x4*>(reinterpret_cast<char*>(sA) + byt) = h;
    }
    __syncthreads();

    const int wave = threadIdx.x >> 6;
    const int lane = threadIdx.x & 63;
    const int lidx = lane & 15;           // row-within-tile for A/B frags; col for C
    const int kb   = (lane >> 4) << 3;    // 0,8,16,24 : k sub-chunk within K=32

    float* outb = out + (size_t)b * NPAIR;

    // 28 lower-triangle tile pairs, exactly 7 per wave
    for (int p = wave * 7, pe = p + 7; p < pe; ++p) {
        int ti = 0;
        while ((ti + 1) * (ti + 2) / 2 <= p) ++ti;
        const int tj = p - ti * (ti + 1) / 2;

        const int ra = ti * 16 + lidx;    // A-operand row (M tile)
        const int rb = tj * 16 + lidx;    // B-operand row (N tile; B = A^T columns)
        const int swzA = (ra & 7) << 4;
        const int swzB = (rb & 7) << 4;

        f32x4 acc = {0.f, 0.f, 0.f, 0.f};
        #pragma unroll
        for (int ks = 0; ks < 4; ++ks) {
            const int kbyte = (ks * 32 + kb) * 2;    // 16B-aligned
            const int offA = ((ra << 8) + kbyte) ^ swzA;
            const int offB = ((rb << 8) + kbyte) ^ swzB;
            bf16x8 av = *reinterpret_cast<const bf16x8*>(
                            reinterpret_cast<char*>(sA) + offA);
            bf16x8 bv = *reinterpret_cast<const bf16x8*>(
                            reinterpret_cast<char*>(sA) + offB);
            acc = __builtin_amdgcn_mfma_f32_16x16x32_bf16(av, bv, acc, 0, 0, 0);
        }

        // C layout (16x16x32): col = lane&15, row = (lane>>4)*4 + reg
        const int col  = tj * 16 + lidx;
        const int row0 = ti * 16 + ((lane >> 4) << 2);
        #pragma unroll
        for (int r = 0; r < 4; ++r) {
            const int row = row0 + r;
            if (row < NB && col < row) {
                outb[row * (row - 1) / 2 + col] = acc[r];
            }
        }
    }
}

extern "C" void kernel_launch(void* const* d_in, const int* in_sizes, int n_in,
                              void* d_out, int out_size, void* d_ws, size_t ws_size,
                              hipStream_t stream) {
    const float* in = (const float*)d_in[0];
    float* out = (float*)d_out;
    const int batch = in_sizes[0] / (NB * DD);
    DotInteraction_82042465288419_kernel<<<batch, 256, 0, stream>>>(in, out);
}

// Round 2
// 132.575 us; speedup vs baseline: 1.0423x; 1.0423x over previous
//
#include <hip/hip_runtime.h>
#include <hip/hip_bf16.h>

// DotInteraction: [8192, 100, 128] f32 -> strict lower triangle of A·A^T -> [8192, 4950] f32
// One block (4 waves) per batch. f32->bf16 swizzled LDS staging, mfma_f32_16x16x32_bf16
// over 28 lower-tri 16x16 tile pairs (7/wave, accumulators held in regs), then
// LDS-repack epilogue -> fully coalesced float2 streaming stores.

#define NB    100
#define DD    128
#define NPAIR 4950   // 100*99/2

typedef __attribute__((ext_vector_type(4))) float  f32x4;
typedef __attribute__((ext_vector_type(2))) float  f32x2;
typedef __attribute__((ext_vector_type(8))) short  bf16x8;
typedef __attribute__((ext_vector_type(4))) short  bf16x4;

__device__ __forceinline__ short f2bf(float x) {
    union { __hip_bfloat16 h; short s; } u; u.h = __float2bfloat16(x);   // RNE
    return u.s;
}

__global__ __launch_bounds__(256, 5)
void DotInteraction_82042465288419_kernel(const float* __restrict__ in,
                                          float* __restrict__ out) {
    // 100 rows x 128 bf16 = 25600 B, XOR-swizzled: byte ^= (row&7)<<4.
    // Reused as f32 sC[4950] (19800 B) in the epilogue.
    __shared__ __align__(16) short sA[NB * DD];

    const int b = blockIdx.x;
    const float* Ab = in + (size_t)b * (NB * DD);

    // ---- stage: f32 -> bf16 into swizzled LDS (coalesced float4 loads) ----
    for (int idx = threadIdx.x; idx < NB * DD / 4; idx += 256) {
        const int r  = idx >> 5;          // 32 float4 per row
        const int k4 = idx & 31;
        f32x4 v = *reinterpret_cast<const f32x4*>(Ab + ((size_t)idx << 2));
        bf16x4 h;
        h.x = f2bf(v.x); h.y = f2bf(v.y); h.z = f2bf(v.z); h.w = f2bf(v.w);
        const int byt = ((r << 8) + (k4 << 3)) ^ ((r & 7) << 4);
        *reinterpret_cast<bf16x4*>(reinterpret_cast<char*>(sA) + byt) = h;
    }
    __syncthreads();

    const int wave = threadIdx.x >> 6;
    const int lane = threadIdx.x & 63;
    const int lidx = lane & 15;           // row-within-tile for A/B frags; col for C
    const int kb   = (lane >> 4) << 3;    // 0,8,16,24 : k sub-chunk within K=32

    f32x4 acc[7];
    int tis[7], tjs[7];

    // 28 lower-triangle tile pairs (7x7 tiles incl. diagonal), exactly 7 per wave.
    #pragma unroll
    for (int pp = 0; pp < 7; ++pp) {
        const int p = wave * 7 + pp;
        int ti = 0;
        while ((ti + 1) * (ti + 2) / 2 <= p) ++ti;
        const int tj = p - ti * (ti + 1) / 2;
        tis[pp] = ti; tjs[pp] = tj;

        int ra = ti * 16 + lidx; if (ra >= NB) ra = NB - 1;  // clamp pad rows (masked later)
        int rb = tj * 16 + lidx; if (rb >= NB) rb = NB - 1;
        const int swzA = (ra & 7) << 4;
        const int swzB = (rb & 7) << 4;

        f32x4 a = {0.f, 0.f, 0.f, 0.f};
        #pragma unroll
        for (int ks = 0; ks < 4; ++ks) {
            const int kbyte = (ks * 32 + kb) * 2;            // 16B-aligned
            const int offA = ((ra << 8) + kbyte) ^ swzA;
            const int offB = ((rb << 8) + kbyte) ^ swzB;
            bf16x8 av = *reinterpret_cast<const bf16x8*>(
                            reinterpret_cast<const char*>(sA) + offA);
            bf16x8 bv = *reinterpret_cast<const bf16x8*>(
                            reinterpret_cast<const char*>(sA) + offB);
            a = __builtin_amdgcn_mfma_f32_16x16x32_bf16(av, bv, a, 0, 0, 0);
        }
        acc[pp] = a;
    }

    __syncthreads();                       // all LDS frag reads done before reuse
    float* sC = reinterpret_cast<float*>(sA);

    // scatter accumulators into packed-triangle LDS (<=2-way bank aliasing, free)
    #pragma unroll
    for (int pp = 0; pp < 7; ++pp) {
        const int col  = tjs[pp] * 16 + lidx;                // C: col = lane&15
        const int row0 = tis[pp] * 16 + ((lane >> 4) << 2);  //    row = (lane>>4)*4 + r
        #pragma unroll
        for (int r = 0; r < 4; ++r) {
            const int row = row0 + r;
            if (row < NB && col < row)
                sC[row * (row - 1) / 2 + col] = acc[pp][r];
        }
    }
    __syncthreads();

    // fully coalesced streaming store: 4950 floats = 2475 float2 (8B-aligned: 19800%8==0)
    float* outb = out + (size_t)b * NPAIR;
    for (int i = threadIdx.x; i < NPAIR / 2; i += 256) {
        *reinterpret_cast<f32x2*>(outb + 2 * i) =
            *reinterpret_cast<const f32x2*>(sC + 2 * i);
    }
}

extern "C" void kernel_launch(void* const* d_in, const int* in_sizes, int n_in,
                              void* d_out, int out_size, void* d_ws, size_t ws_size,
                              hipStream_t stream) {
    const float* in = (const float*)d_in[0];
    float* out = (float*)d_out;
    const int batch = in_sizes[0] / (NB * DD);
    DotInteraction_82042465288419_kernel<<<batch, 256, 0, stream>>>(in, out);
}

// Round 3
// 98.635 us; speedup vs baseline: 1.4010x; 1.3441x over previous
//
#include <hip/hip_runtime.h>
#include <hip/hip_bf16.h>

// DotInteraction: [8192, 100, 128] f32 -> strict lower triangle of A·A^T -> [8192, 4950] f32
// One block (4 waves) per batch. Issue-early NT loads -> f32->bf16 swizzled LDS staging,
// mfma_f32_16x16x32_bf16 over 28 lower-tri tile pairs (7/wave, row-major order with
// A-fragment register caching), LDS repack -> coalesced NT float2 streaming stores.

#define NB    100
#define DD    128
#define NPAIR 4950   // 100*99/2

typedef __attribute__((ext_vector_type(4))) float  f32x4;
typedef __attribute__((ext_vector_type(2))) float  f32x2;
typedef __attribute__((ext_vector_type(8))) short  bf16x8;
typedef __attribute__((ext_vector_type(4))) short  bf16x4;

__device__ __forceinline__ short f2bf(float x) {
    union { __hip_bfloat16 h; short s; } u; u.h = __float2bfloat16(x);   // RNE
    return u.s;
}

// swizzled LDS fragment address: row rr, k-chunk byte kbyte (16B-aligned)
#define FRAG_AT(base_sA, rr, kbyte) \
    (*reinterpret_cast<const bf16x8*>(reinterpret_cast<const char*>(base_sA) + \
        ((((rr) << 8) + (kbyte)) ^ (((rr) & 7) << 4))))

__global__ __launch_bounds__(256, 6)
void DotInteraction_82042465288419_kernel(const float* __restrict__ in,
                                          float* __restrict__ out) {
    // 100 x 128 bf16 = 25600 B, XOR-swizzled: byte ^= (row&7)<<4. Reused as f32 sC[4950].
    __shared__ __align__(16) short sA[NB * DD];

    const int tid = threadIdx.x;
    const int b = blockIdx.x;
    const float* Ab = in + (size_t)b * (NB * DD);
    const f32x4* Ab4 = reinterpret_cast<const f32x4*>(Ab);

    // ---- stage: issue ALL loads first (deep vmcnt pipeline), then cvt + ds_write ----
    f32x4 v[12];
    #pragma unroll
    for (int it = 0; it < 12; ++it)
        v[it] = __builtin_nontemporal_load(Ab4 + (tid + it * 256));
    f32x4 vt;
    if (tid < 128) vt = __builtin_nontemporal_load(Ab4 + (3072 + tid));

    #pragma unroll
    for (int it = 0; it < 12; ++it) {
        const int idx = tid + it * 256;
        const int r = idx >> 5, k4 = idx & 31;        // 32 float4 per row
        bf16x4 h;
        h.x = f2bf(v[it].x); h.y = f2bf(v[it].y); h.z = f2bf(v[it].z); h.w = f2bf(v[it].w);
        const int byt = ((r << 8) + (k4 << 3)) ^ ((r & 7) << 4);
        *reinterpret_cast<bf16x4*>(reinterpret_cast<char*>(sA) + byt) = h;
    }
    if (tid < 128) {
        const int idx = 3072 + tid;
        const int r = idx >> 5, k4 = idx & 31;
        bf16x4 h;
        h.x = f2bf(vt.x); h.y = f2bf(vt.y); h.z = f2bf(vt.z); h.w = f2bf(vt.w);
        const int byt = ((r << 8) + (k4 << 3)) ^ ((r & 7) << 4);
        *reinterpret_cast<bf16x4*>(reinterpret_cast<char*>(sA) + byt) = h;
    }
    __syncthreads();

    const int wave = __builtin_amdgcn_readfirstlane(tid >> 6);  // SGPR: p/ti/tj scalar
    const int lane = tid & 63;
    const int lidx = lane & 15;           // row-within-tile for frags; col for C
    const int kb2  = ((lane >> 4) << 3) * 2;  // byte offset of k sub-chunk within K=32

    f32x4 acc[7];
    int tis[7], tjs[7];
    bf16x8 aF0, aF1, aF2, aF3;            // A-fragment cache (reload only on ti change)
    int prev_ti = -1;

    // 28 lower-tri tile pairs in row-major order -> consecutive pairs share ti
    #pragma unroll
    for (int pp = 0; pp < 7; ++pp) {
        const int p = wave * 7 + pp;
        int ti = 0;
        while ((ti + 1) * (ti + 2) / 2 <= p) ++ti;
        const int tj = p - ti * (ti + 1) / 2;
        tis[pp] = ti; tjs[pp] = tj;

        if (ti != prev_ti) {
            int ra = ti * 16 + lidx; if (ra >= NB) ra = NB - 1;  // clamp pad rows (masked later)
            aF0 = FRAG_AT(sA, ra, 0 * 64 + kb2);
            aF1 = FRAG_AT(sA, ra, 1 * 64 + kb2);
            aF2 = FRAG_AT(sA, ra, 2 * 64 + kb2);
            aF3 = FRAG_AT(sA, ra, 3 * 64 + kb2);
            prev_ti = ti;
        }

        int rb = tj * 16 + lidx; if (rb >= NB) rb = NB - 1;
        f32x4 a = {0.f, 0.f, 0.f, 0.f};
        a = __builtin_amdgcn_mfma_f32_16x16x32_bf16(aF0, FRAG_AT(sA, rb, 0 * 64 + kb2), a, 0, 0, 0);
        a = __builtin_amdgcn_mfma_f32_16x16x32_bf16(aF1, FRAG_AT(sA, rb, 1 * 64 + kb2), a, 0, 0, 0);
        a = __builtin_amdgcn_mfma_f32_16x16x32_bf16(aF2, FRAG_AT(sA, rb, 2 * 64 + kb2), a, 0, 0, 0);
        a = __builtin_amdgcn_mfma_f32_16x16x32_bf16(aF3, FRAG_AT(sA, rb, 3 * 64 + kb2), a, 0, 0, 0);
        acc[pp] = a;
    }

    __syncthreads();                       // all frag reads done before LDS reuse
    float* sC = reinterpret_cast<float*>(sA);

    // scatter accumulators into packed-triangle LDS (<=2-way aliasing, free)
    #pragma unroll
    for (int pp = 0; pp < 7; ++pp) {
        const int col  = tjs[pp] * 16 + lidx;                // C: col = lane&15
        const int row0 = tis[pp] * 16 + ((lane >> 4) << 2);  //    row = (lane>>4)*4 + r
        #pragma unroll
        for (int r = 0; r < 4; ++r) {
            const int row = row0 + r;
            if (row < NB && col < row)
                sC[row * (row - 1) / 2 + col] = acc[pp][r];
        }
    }
    __syncthreads();

    // fully coalesced NT streaming store: 4950 floats = 2475 float2 (19800 % 8 == 0)
    float* outb = out + (size_t)b * NPAIR;
    for (int i = tid; i < NPAIR / 2; i += 256) {
        f32x2 w = *reinterpret_cast<const f32x2*>(sC + 2 * i);
        __builtin_nontemporal_store(w, reinterpret_cast<f32x2*>(outb + 2 * i));
    }
}

extern "C" void kernel_launch(void* const* d_in, const int* in_sizes, int n_in,
                              void* d_out, int out_size, void* d_ws, size_t ws_size,
                              hipStream_t stream) {
    const float* in = (const float*)d_in[0];
    float* out = (float*)d_out;
    const int batch = in_sizes[0] / (NB * DD);
    DotInteraction_82042465288419_kernel<<<batch, 256, 0, stream>>>(in, out);
}